// Round 2
// baseline (196.232 us; speedup 1.0000x reference)
//
#include <hip/hip_runtime.h>

#define BB 16
#define TT 8192
#define NN 128                     // N_PRE == N_POST
constexpr int CHUNK = 256;         // time-steps per chunk
constexpr int NCH   = BB * TT / CHUNK;   // 512 chunks
constexpr int NBLK  = NCH / 2;           // 256 blocks, 2 chunks each
constexpr int OUTN  = NN * NN;           // 16384
constexpr int GS    = 264;         // bufG row stride in halves (528 B, 16B-aligned)
constexpr int SLOTS = OUTN / 2;    // 8192 packed u32 slots per block-slice
constexpr int PROWS = 315;         // staged post rows per chunk: (t0, t0+315]
constexpr int NWAVE = 16;          // 1024 threads
constexpr int WIN   = CHUNK / NWAVE;     // 16-step filter window per wave

typedef _Float16 f16x8 __attribute__((ext_vector_type(8)));
typedef _Float16 f16x2 __attribute__((ext_vector_type(2)));
typedef float    f32x4 __attribute__((ext_vector_type(4)));

__device__ __forceinline__ unsigned short h16(float x) {
    _Float16 h = (_Float16)x;
    return __builtin_bit_cast(unsigned short, h);
}
__device__ __forceinline__ unsigned int pack2(float x, float y) {
    return (unsigned int)h16(x) | ((unsigned int)h16(y) << 16);
}
__device__ __forceinline__ float2 ldL(const unsigned short* p_lds, int m, int q0) {
    const unsigned int v = *(const unsigned int*)&p_lds[m * NN + q0];
    const f16x2 h = __builtin_bit_cast(f16x2, v);
    return make_float2((float)h[0], (float)h[1]);
}

// grid 256 x 1024 threads, 1 block/CU (156 KB LDS), 16 waves = 4 waves/SIMD.
// ROUND-1 FIX: __launch_bounds__(1024) WITHOUT a min-waves arg. The previous
// (1024,4) capped VGPRs at 64 -> ~100 MB of scratch spill traffic (WRITE_SIZE
// 10->109 MB) and 91 us. Plain (1024) guarantees "one block fits" -> 128 VGPR
// cap, which this kernel's live state fits (ancestor fit 128 with MORE state).
// Pipeline: stage c0 -> issue c1 loads -> filter c0 (overlaps c1 drain) ->
// g0 dump -> barrier -> c1 regs->bufP -> MFMA c0 -> barrier -> filter c1 ->
// g1 dump -> barrier -> MFMA c1 (acc over both) -> per-wave partial write.
template<bool ATOMIC>
__global__ __launch_bounds__(1024)
void stdp_main(const float* __restrict__ pre, const float* __restrict__ post,
               const int* __restrict__ dtp,
               unsigned int* __restrict__ part, float* __restrict__ wpost,
               float* __restrict__ outat)
{
    __shared__ __align__(16) unsigned short bufP[PROWS * NN];   // 80,640 B post tile
    __shared__ __align__(16) unsigned short bufG[NN * GS];      // 67,584 B g tile
    __shared__ float lds_ps[NWAVE * NN];                        // 8 KB

    const int tid    = threadIdx.x;
    const int bi     = blockIdx.x;
    const int c0g    = bi * 2;           // global chunk ids c0g, c0g+1 (same batch)
    const int b      = c0g >> 5;
    const int chunk0 = c0g & 31;         // even, 0..30
    const int t00    = chunk0 * CHUNK;
    const int t01    = t00 + CHUNK;
    const int wv     = tid >> 6;         // wave 0..15
    const int lane   = tid & 63;

    const float dtf = (float)(*dtp);
    const float r   = expf(-dtf * (1.0f / 20.0f));

    const float* pb = post + (size_t)b * TT * NN;
    const float* ab = pre  + (size_t)b * TT * NN;

    const int sc = tid & 31;             // staging: float4 column
    const int mr = tid >> 5;             // staging: starting row (0..31)

    // ---------- stage c0 post tile into bufP ----------
    for (int m = mr; m < PROWS; m += 32) {
        const int t = t00 + 1 + m;       // c0 even => t00+315 <= 7995 < TT, no guard needed
        const float4 v = *(const float4*)(pb + (size_t)t * NN + sc * 4);
        *(uint2*)&bufP[m * NN + sc * 4] = make_uint2(pack2(v.x, v.y), pack2(v.z, v.w));
    }
    __syncthreads();

    // ---------- issue c1 staging loads into registers (drain overlaps filter c0) ----------
    float4 va[10];
    #pragma unroll
    for (int i = 0; i < 10; ++i) {
        const int m = mr + i * 32;
        const int t = t01 + 1 + m;
        va[i] = make_float4(0.f, 0.f, 0.f, 0.f);
        if (m < PROWS && t < TT) va[i] = *(const float4*)(pb + (size_t)t * NN + sc * 4);
    }

    const int q0   = lane * 2;
    const int base = wv * WIN;           // window start (16 steps per wave)

    // ---------- filter: window WIN steps, 2 q per lane ----------
    unsigned int pk0[8], pk1[8];
    float ps0, ps1;
    // Startup g[c=15] = sum_{tau=1..59} r^tau * P[base+14+tau], 4 strided ILP
    // chains (dep depth 15 instead of 58). Then backward recurrence c=14..0:
    // g[c] = r*(g[c+1] + P[base+c]) - r^60 * P[base+c+59].
    #define FILTER_PHASE(SRC) {                                               \
        const float r2 = r * r, r3 = r2 * r, r4 = r2 * r2;                    \
        float2 p = ldL(SRC, base + 15, q0);      /* tau=1 */                  \
        ps0 = p.x; ps1 = p.y;                                                 \
        float gx0 = r  * p.x, gy0 = r  * p.y;                                 \
        p = ldL(SRC, base + 16, q0);             /* tau=2 */                  \
        float gx1 = r2 * p.x, gy1 = r2 * p.y;                                 \
        p = ldL(SRC, base + 17, q0);             /* tau=3 */                  \
        float gx2 = r3 * p.x, gy2 = r3 * p.y;                                 \
        p = ldL(SRC, base + 18, q0);             /* tau=4 */                  \
        float gx3 = r4 * p.x, gy3 = r4 * p.y;                                 \
        float wA = r * r4, wB = r2 * r4, wC = r3 * r4, wD = r4 * r4;          \
        _Pragma("unroll")                                                     \
        for (int j = 1; j < 15; ++j) {                                        \
            p = ldL(SRC, base + 15 + 4 * j, q0);                              \
            gx0 = fmaf(wA, p.x, gx0); gy0 = fmaf(wA, p.y, gy0);               \
            p = ldL(SRC, base + 16 + 4 * j, q0);                              \
            gx1 = fmaf(wB, p.x, gx1); gy1 = fmaf(wB, p.y, gy1);               \
            p = ldL(SRC, base + 17 + 4 * j, q0);                              \
            gx2 = fmaf(wC, p.x, gx2); gy2 = fmaf(wC, p.y, gy2);               \
            if (j < 14) {                                                     \
                p = ldL(SRC, base + 18 + 4 * j, q0);                          \
                gx3 = fmaf(wD, p.x, gx3); gy3 = fmaf(wD, p.y, gy3);           \
            }                                                                 \
            wA *= r4; wB *= r4; wC *= r4; wD *= r4;                           \
        }                                                                     \
        const float r8 = r4 * r4, r16 = r8 * r8, r32 = r16 * r16;             \
        const float r60 = ((r32 * r16) * r8) * r4;                            \
        float gx = (gx0 + gx1) + (gx2 + gx3);                                 \
        float gy = (gy0 + gy1) + (gy2 + gy3);                                 \
        pk0[7] = (unsigned int)h16(gx) << 16;                                 \
        pk1[7] = (unsigned int)h16(gy) << 16;                                 \
        _Pragma("unroll")                                                     \
        for (int c = 14; c >= 0; --c) {                                       \
            const float2 p1  = ldL(SRC, base + c,      q0);                   \
            const float2 p60 = ldL(SRC, base + c + 59, q0);                   \
            gx = r * (gx + p1.x) - r60 * p60.x;                               \
            gy = r * (gy + p1.y) - r60 * p60.y;                               \
            ps0 += p1.x; ps1 += p1.y;                                         \
            if (c & 1) {                                                      \
                pk0[c >> 1] = (unsigned int)h16(gx) << 16;                    \
                pk1[c >> 1] = (unsigned int)h16(gy) << 16;                    \
            } else {                                                          \
                pk0[c >> 1] |= h16(gx);                                       \
                pk1[c >> 1] |= h16(gy);                                       \
            }                                                                 \
        }                                                                     \
    }
    #define DUMP_G() {                                                        \
        unsigned short* d0 = &bufG[q0 * GS + base];                           \
        unsigned short* d1 = &bufG[(q0 + 1) * GS + base];                     \
        *(uint4*)(d0)     = make_uint4(pk0[0], pk0[1], pk0[2], pk0[3]);       \
        *(uint4*)(d0 + 8) = make_uint4(pk0[4], pk0[5], pk0[6], pk0[7]);       \
        *(uint4*)(d1)     = make_uint4(pk1[0], pk1[1], pk1[2], pk1[3]);       \
        *(uint4*)(d1 + 8) = make_uint4(pk1[4], pk1[5], pk1[6], pk1[7]);       \
        lds_ps[wv * NN + q0]     = ps0;                                       \
        lds_ps[wv * NN + q0 + 1] = ps1;                                       \
    }

    FILTER_PHASE(bufP)
    DUMP_G()
    __syncthreads();                     // bufP reads done; g0 + ps visible; c1 loads drained

    // ---------- store c1 post tile into bufP (safe: filter c0 complete) ----------
    #pragma unroll
    for (int i = 0; i < 10; ++i) {
        const int m = mr + i * 32;
        if (m < PROWS)
            *(uint2*)&bufP[m * NN + sc * 4] =
                make_uint2(pack2(va[i].x, va[i].y), pack2(va[i].z, va[i].w));
    }

    // ---------- wpost c0 ----------
    if (tid < NN) {
        float s = 0.f;
        #pragma unroll
        for (int w = 0; w < NWAVE; ++w) s += lds_ps[w * NN + tid];
        if (chunk0 == 0) s += pb[tid];   // window (t0,t0+256] misses t=0 row once per batch
        if constexpr (ATOMIC) atomicAdd(&wpost[tid], s);
        else wpost[(size_t)tid * NCH + c0g] = s;
    }

    // ---------- MFMA: wave pair (wv, wv+8) shares pre rows, splits qt ----------
    const int pr0 = (wv & 7) * 16;
    const int qtb = (wv >> 3) * 4;
    f32x4 acc[4];
    #pragma unroll
    for (int qi = 0; qi < 4; ++qi) acc[qi] = (f32x4){0.f, 0.f, 0.f, 0.f};

    #define MFMA_PHASE(T0) {                                                  \
        const float* abase = ab + (size_t)((T0) + (lane >> 4) * 8) * NN + pr0 + (lane & 15); \
        float an[8];                                                          \
        _Pragma("unroll")                                                     \
        for (int j = 0; j < 8; ++j) an[j] = abase[(size_t)j * NN];            \
        _Pragma("unroll")                                                     \
        for (int ks = 0; ks < 8; ++ks) {                                      \
            f16x8 af;                                                         \
            _Pragma("unroll")                                                 \
            for (int j = 0; j < 8; ++j) af[j] = (_Float16)an[j];              \
            if (ks < 7) {                                                     \
                const float* src = abase + (size_t)((ks + 1) * 32) * NN;      \
                _Pragma("unroll")                                             \
                for (int j = 0; j < 8; ++j) an[j] = src[(size_t)j * NN];      \
            }                                                                 \
            const int koff = ks * 32 + (lane >> 4) * 8;                       \
            _Pragma("unroll")                                                 \
            for (int qi = 0; qi < 4; ++qi) {                                  \
                const f16x8 bf = *(const f16x8*)&bufG[((qtb + qi) * 16 + (lane & 15)) * GS + koff]; \
                acc[qi] = __builtin_amdgcn_mfma_f32_16x16x32_f16(af, bf, acc[qi], 0, 0, 0); \
            }                                                                 \
        }                                                                     \
    }

    MFMA_PHASE(t00)
    __syncthreads();                     // bufG reads done; bufP(c1) stores visible

    // ---------- filter c1 + dump g1 ----------
    FILTER_PHASE(bufP)
    DUMP_G()
    __syncthreads();

    // ---------- wpost c1 ----------
    if (tid < NN) {
        float s = 0.f;
        #pragma unroll
        for (int w = 0; w < NWAVE; ++w) s += lds_ps[w * NN + tid];
        if constexpr (ATOMIC) atomicAdd(&wpost[tid], s);
        else wpost[(size_t)tid * NCH + c0g + 1] = s;
    }

    // ---------- MFMA c1 (accumulates onto acc) ----------
    MFMA_PHASE(t01)

    // ---------- write partial: wave pair fills disjoint qt of slice (wv&7) ----------
    if constexpr (!ATOMIC) {
        unsigned int* dst = part + ((size_t)bi * 8 + (wv & 7)) * 1024 + lane;
        #pragma unroll
        for (int qi = 0; qi < 4; ++qi) {
            const int qt = qtb + qi;
            dst[qt * 128]      = pack2(acc[qi][0], acc[qi][1]);
            dst[qt * 128 + 64] = pack2(acc[qi][2], acc[qi][3]);
        }
    } else {
        #pragma unroll
        for (int qi = 0; qi < 4; ++qi)
            #pragma unroll
            for (int rg = 0; rg < 4; ++rg) {
                const int prow = pr0 + (lane >> 4) * 4 + rg;
                const int qcol = (qtb + qi) * 16 + (lane & 15);
                atomicAdd(&outat[prow * NN + qcol], acc[qi][rg]);
            }
    }
    #undef FILTER_PHASE
    #undef DUMP_G
    #undef MFMA_PHASE
}

// fused split-K reduce + hfac + epilogue: 128 blocks x 512 thr.
// Each block's 64 slots share one qt => 16 distinct q: hfac computed in-kernel.
__global__ __launch_bounds__(512)
void finalize_ws(const unsigned int* __restrict__ part, const float* __restrict__ wpost,
                 const int* __restrict__ dtp, const float* __restrict__ W,
                 float* __restrict__ out)
{
    __shared__ float2 red[512];
    __shared__ float  hfs[16];
    const int s    = threadIdx.x & 63;        // slot within block's 64
    const int kq   = threadIdx.x >> 6;        // 0..7
    const int slot = blockIdx.x * 64 + s;     // 0..8191
    const int qt   = (slot >> 7) & 7;         // fixed for whole block
    const int qbase = qt * 16;

    // hfac: 32 threads per q, shfl reduce over wpost[q][0..NCH)
    {
        const int qi = threadIdx.x >> 5;      // 0..15
        const int pr = threadIdx.x & 31;
        float hsum = 0.f;
        const float* wq = wpost + (size_t)(qbase + qi) * NCH;
        #pragma unroll 4
        for (int k = pr; k < NCH; k += 32) hsum += wq[k];
        #pragma unroll
        for (int off = 16; off; off >>= 1) hsum += __shfl_down(hsum, off, 32);
        if (pr == 0) {
            const float dtf   = (float)(*dtp);
            const float alpha = dtf * 1e-3f;
            hfs[qi] = -0.001f * (alpha * (hsum * (1.0f / (float)(BB * TT)) - 0.1f));
        }
    }

    float sx = 0.f, sy = 0.f;
    #pragma unroll 8
    for (int k = kq * (NBLK / 8); k < (kq + 1) * (NBLK / 8); ++k) {
        const unsigned int v = part[(size_t)k * SLOTS + slot];
        const f16x2 h = __builtin_bit_cast(f16x2, v);
        sx += (float)h[0];
        sy += (float)h[1];
    }
    red[threadIdx.x] = make_float2(sx, sy);
    __syncthreads();
    if (threadIdx.x < 64) {
        float tx = red[s].x, ty = red[s].y;
        #pragma unroll
        for (int g = 1; g < 8; ++g) {
            const float2 v = red[g * 64 + s];
            tx += v.x; ty += v.y;
        }
        // un-permute slot -> (p, q)
        const int lane = slot & 63;
        const int rp   = (slot >> 6) & 1;
        const int wv   = slot >> 10;
        const int p    = wv * 16 + ((lane >> 4) << 2) + rp * 2;
        const int qi   = lane & 15;
        const int q    = qbase + qi;
        const float scale = (float)((0.005 - 0.00525) / (double)(BB * TT));
        const float hf = hfs[qi];
        out[p * NN + q]       = fmaf(tx, scale, hf * W[p * NN + q]);
        out[(p + 1) * NN + q] = fmaf(ty, scale, hf * W[(p + 1) * NN + q]);
    }
}

// fallback epilogue when S was atomically accumulated in d_out
__global__ void finalize_at(const float* __restrict__ wpost, const int* __restrict__ dtp,
                            const float* __restrict__ W, float* __restrict__ out)
{
    const int i = (blockIdx.x * 256 + threadIdx.x) * 2;
    const int q = i & 127;
    const float scale = (float)((0.005 - 0.00525) / (double)(BB * TT));
    const float dtf   = (float)(*dtp);
    const float alpha = dtf * 1e-3f;
    const float inv   = 1.0f / (float)(BB * TT);
    const float hf0   = -0.001f * (alpha * (wpost[q]     * inv - 0.1f));
    const float hf1   = -0.001f * (alpha * (wpost[q + 1] * inv - 0.1f));
    float2 sv = *(const float2*)(out + i);
    float2 w  = *(const float2*)(W + i);
    float2 o;
    o.x = fmaf(sv.x, scale, hf0 * w.x);
    o.y = fmaf(sv.y, scale, hf1 * w.y);
    *(float2*)(out + i) = o;
}

extern "C" void kernel_launch(void* const* d_in, const int* in_sizes, int n_in,
                              void* d_out, int out_size, void* d_ws, size_t ws_size,
                              hipStream_t stream)
{
    const float* pre  = (const float*)d_in[0];
    const float* post = (const float*)d_in[1];
    const float* W    = (const float*)d_in[2];
    const int*   dtp  = (const int*)d_in[3];
    float* out = (float*)d_out;

    const size_t part_bytes  = (size_t)NBLK * SLOTS * sizeof(unsigned int); // 8 MiB
    const size_t wpost_bytes = (size_t)NN * NCH * sizeof(float);            // 256 KiB
    const size_t need = part_bytes + wpost_bytes;

    if (ws_size >= need) {
        unsigned int* part = (unsigned int*)d_ws;
        float* wpost       = (float*)((char*)d_ws + part_bytes);
        hipLaunchKernelGGL((stdp_main<false>), dim3(NBLK), dim3(1024), 0, stream,
                           pre, post, dtp, part, wpost, (float*)nullptr);
        hipLaunchKernelGGL(finalize_ws, dim3(SLOTS / 64), dim3(512), 0, stream,
                           part, wpost, dtp, W, out);
    } else {
        // atomic fallback: needs only 512 B of workspace
        float* wpost = (float*)d_ws;
        hipMemsetAsync(d_out, 0, OUTN * sizeof(float), stream);
        hipMemsetAsync(wpost, 0, NN * sizeof(float), stream);
        hipLaunchKernelGGL((stdp_main<true>), dim3(NBLK), dim3(1024), 0, stream,
                           pre, post, dtp, (unsigned int*)nullptr, wpost, out);
        hipLaunchKernelGGL(finalize_at, dim3(OUTN / 512), dim3(256), 0, stream,
                           wpost, dtp, W, out);
    }
}

// Round 3
// 172.759 us; speedup vs baseline: 1.1359x; 1.1359x over previous
//
#include <hip/hip_runtime.h>

#define BB 16
#define TT 8192
#define NN 128                     // N_PRE == N_POST
constexpr int CHUNK = 256;         // time-steps per chunk
constexpr int NCH   = BB * TT / CHUNK;   // 512 chunks
constexpr int NBLK  = NCH / 2;           // 256 blocks, 2 chunks each
constexpr int OUTN  = NN * NN;           // 16384
constexpr int GS    = 264;         // bufG row stride in halves (528 B, 16B-aligned)
constexpr int SLOTS = OUTN / 2;    // 8192 packed u32 slots per block-slice
constexpr int PROWS = 315;         // staged post rows per chunk: (t0, t0+315]
constexpr int NWAVE = 16;          // 1024 threads
constexpr int WIN   = CHUNK / NWAVE;     // 16-step filter window per wave

typedef _Float16 f16x8 __attribute__((ext_vector_type(8)));
typedef _Float16 f16x2 __attribute__((ext_vector_type(2)));
typedef float    f32x4 __attribute__((ext_vector_type(4)));

__device__ __forceinline__ unsigned short h16(float x) {
    _Float16 h = (_Float16)x;
    return __builtin_bit_cast(unsigned short, h);
}
__device__ __forceinline__ unsigned int pack2(float x, float y) {
    return (unsigned int)h16(x) | ((unsigned int)h16(y) << 16);
}
__device__ __forceinline__ float2 ldL(const unsigned short* p_lds, int m, int q0) {
    const unsigned int v = *(const unsigned int*)&p_lds[m * NN + q0];
    const f16x2 h = __builtin_bit_cast(f16x2, v);
    return make_float2((float)h[0], (float)h[1]);
}

// grid 256 x 1024 threads, 1 block/CU (156 KB LDS), 16 waves = 4 waves/SIMD.
// ROUND-3: the backend pins 16-wave blocks at 64 VGPR (rounds 1-2: ~100 MB
// scratch spill). Instead of fighting the allocator, fit in 64 VGPRs:
//   - no va[] register prefetch of c1 (was 40 VGPRs): direct stage after bar
//   - no pk0/pk1 packing arrays (was 16 VGPRs): stream g pairs to bufG
//     during the backward recurrence (one u32 store per even step)
// Peak live state ~55 regs -> no spill at the compiler's 64-cap.
// Pipeline: stage c0 -> filter c0 -> barrier -> stage c1 -> wpost c0 ->
// MFMA c0 -> barrier -> filter c1 -> barrier -> wpost c1 -> MFMA c1 ->
// per-wave-pair partial write.
template<bool ATOMIC>
__global__ __launch_bounds__(1024)
void stdp_main(const float* __restrict__ pre, const float* __restrict__ post,
               const int* __restrict__ dtp,
               unsigned int* __restrict__ part, float* __restrict__ wpost,
               float* __restrict__ outat)
{
    __shared__ __align__(16) unsigned short bufP[PROWS * NN];   // 80,640 B post tile
    __shared__ __align__(16) unsigned short bufG[NN * GS];      // 67,584 B g tile
    __shared__ float lds_ps[NWAVE * NN];                        // 8 KB

    const int tid    = threadIdx.x;
    const int bi     = blockIdx.x;
    const int c0g    = bi * 2;           // global chunk ids c0g, c0g+1 (same batch)
    const int b      = c0g >> 5;
    const int chunk0 = c0g & 31;         // even, 0..30
    const int t00    = chunk0 * CHUNK;
    const int t01    = t00 + CHUNK;
    const int wv     = tid >> 6;         // wave 0..15
    const int lane   = tid & 63;

    const float dtf = (float)(*dtp);
    const float r   = expf(-dtf * (1.0f / 20.0f));

    const float* pb = post + (size_t)b * TT * NN;
    const float* ab = pre  + (size_t)b * TT * NN;

    const int sc = tid & 31;             // staging: float4 column
    const int mr = tid >> 5;             // staging: starting row (0..31)

    // ---------- stage c0 post tile into bufP ----------
    for (int m = mr; m < PROWS; m += 32) {
        const int t = t00 + 1 + m;       // c0 even => t00+315 <= 7995 < TT, no guard needed
        const float4 v = *(const float4*)(pb + (size_t)t * NN + sc * 4);
        *(uint2*)&bufP[m * NN + sc * 4] = make_uint2(pack2(v.x, v.y), pack2(v.z, v.w));
    }
    __syncthreads();

    const int q0   = lane * 2;
    const int base = wv * WIN;           // window start (16 steps per wave)

    // ---------- filter: window WIN steps, 2 q per lane, streaming dump ----------
    float ps0, ps1;
    // Startup g[15] = sum_{tau=1..59} r^tau * P[base+14+tau], 4 strided ILP
    // chains (dep depth 15). Then backward recurrence c=14..0:
    // g[c] = r*(g[c+1] + P[base+c]) - r^60 * P[base+c+59];
    // write pack2(g[c], g[c+1]) to bufG at even c (g[c+1] kept in gk).
    #define FILTER_PHASE(SRC) {                                               \
        const float r2 = r * r, r3 = r2 * r, r4 = r2 * r2;                    \
        float2 p = ldL(SRC, base + 15, q0);      /* tau=1 */                  \
        ps0 = p.x; ps1 = p.y;                                                 \
        float gx0 = r  * p.x, gy0 = r  * p.y;                                 \
        p = ldL(SRC, base + 16, q0);             /* tau=2 */                  \
        float gx1 = r2 * p.x, gy1 = r2 * p.y;                                 \
        p = ldL(SRC, base + 17, q0);             /* tau=3 */                  \
        float gx2 = r3 * p.x, gy2 = r3 * p.y;                                 \
        p = ldL(SRC, base + 18, q0);             /* tau=4 */                  \
        float gx3 = r4 * p.x, gy3 = r4 * p.y;                                 \
        float wA = r * r4, wB = r2 * r4, wC = r3 * r4, wD = r4 * r4;          \
        _Pragma("unroll")                                                     \
        for (int j = 1; j < 15; ++j) {                                        \
            p = ldL(SRC, base + 15 + 4 * j, q0);                              \
            gx0 = fmaf(wA, p.x, gx0); gy0 = fmaf(wA, p.y, gy0);               \
            p = ldL(SRC, base + 16 + 4 * j, q0);                              \
            gx1 = fmaf(wB, p.x, gx1); gy1 = fmaf(wB, p.y, gy1);               \
            p = ldL(SRC, base + 17 + 4 * j, q0);                              \
            gx2 = fmaf(wC, p.x, gx2); gy2 = fmaf(wC, p.y, gy2);               \
            if (j < 14) {                                                     \
                p = ldL(SRC, base + 18 + 4 * j, q0);                          \
                gx3 = fmaf(wD, p.x, gx3); gy3 = fmaf(wD, p.y, gy3);           \
            }                                                                 \
            wA *= r4; wB *= r4; wC *= r4; wD *= r4;                           \
        }                                                                     \
        const float r8 = r4 * r4, r16 = r8 * r8, r32 = r16 * r16;             \
        const float r60 = ((r32 * r16) * r8) * r4;                            \
        float gx = (gx0 + gx1) + (gx2 + gx3);                                 \
        float gy = (gy0 + gy1) + (gy2 + gy3);                                 \
        float gkx = gx, gky = gy;                 /* g[15] */                 \
        unsigned short* d0 = &bufG[q0 * GS + base];                           \
        unsigned short* d1 = &bufG[(q0 + 1) * GS + base];                     \
        _Pragma("unroll")                                                     \
        for (int c = 14; c >= 0; --c) {                                       \
            const float2 p1  = ldL(SRC, base + c,      q0);                   \
            const float2 p60 = ldL(SRC, base + c + 59, q0);                   \
            gx = r * (gx + p1.x) - r60 * p60.x;                               \
            gy = r * (gy + p1.y) - r60 * p60.y;                               \
            ps0 += p1.x; ps1 += p1.y;                                         \
            if (c & 1) {                                                      \
                gkx = gx; gky = gy;                                           \
            } else {                                                          \
                *(unsigned int*)(d0 + c) = pack2(gx, gkx);                    \
                *(unsigned int*)(d1 + c) = pack2(gy, gky);                    \
            }                                                                 \
        }                                                                     \
        lds_ps[wv * NN + q0]     = ps0;                                       \
        lds_ps[wv * NN + q0 + 1] = ps1;                                       \
    }

    FILTER_PHASE(bufP)
    __syncthreads();                     // bufP reads done; g0 + ps visible

    // ---------- stage c1 post tile into bufP (direct, no reg prefetch) ----------
    for (int m = mr; m < PROWS; m += 32) {
        const int t = t01 + 1 + m;       // c1 odd: t can exceed TT-1 -> zero-pad
        float4 v = make_float4(0.f, 0.f, 0.f, 0.f);
        if (t < TT) v = *(const float4*)(pb + (size_t)t * NN + sc * 4);
        *(uint2*)&bufP[m * NN + sc * 4] =
            make_uint2(pack2(v.x, v.y), pack2(v.z, v.w));
    }

    // ---------- wpost c0 ----------
    if (tid < NN) {
        float s = 0.f;
        #pragma unroll
        for (int w = 0; w < NWAVE; ++w) s += lds_ps[w * NN + tid];
        if (chunk0 == 0) s += pb[tid];   // window (t0,t0+256] misses t=0 row once per batch
        if constexpr (ATOMIC) atomicAdd(&wpost[tid], s);
        else wpost[(size_t)tid * NCH + c0g] = s;
    }

    // ---------- MFMA: wave pair (wv, wv+8) shares pre rows, splits qt ----------
    const int pr0 = (wv & 7) * 16;
    const int qtb = (wv >> 3) * 4;
    f32x4 acc[4];
    #pragma unroll
    for (int qi = 0; qi < 4; ++qi) acc[qi] = (f32x4){0.f, 0.f, 0.f, 0.f};

    #define MFMA_PHASE(T0) {                                                  \
        const float* abase = ab + (size_t)((T0) + (lane >> 4) * 8) * NN + pr0 + (lane & 15); \
        float an[8];                                                          \
        _Pragma("unroll")                                                     \
        for (int j = 0; j < 8; ++j) an[j] = abase[(size_t)j * NN];            \
        _Pragma("unroll")                                                     \
        for (int ks = 0; ks < 8; ++ks) {                                      \
            f16x8 af;                                                         \
            _Pragma("unroll")                                                 \
            for (int j = 0; j < 8; ++j) af[j] = (_Float16)an[j];              \
            if (ks < 7) {                                                     \
                const float* src = abase + (size_t)((ks + 1) * 32) * NN;      \
                _Pragma("unroll")                                             \
                for (int j = 0; j < 8; ++j) an[j] = src[(size_t)j * NN];      \
            }                                                                 \
            const int koff = ks * 32 + (lane >> 4) * 8;                       \
            _Pragma("unroll")                                                 \
            for (int qi = 0; qi < 4; ++qi) {                                  \
                const f16x8 bf = *(const f16x8*)&bufG[((qtb + qi) * 16 + (lane & 15)) * GS + koff]; \
                acc[qi] = __builtin_amdgcn_mfma_f32_16x16x32_f16(af, bf, acc[qi], 0, 0, 0); \
            }                                                                 \
        }                                                                     \
    }

    MFMA_PHASE(t00)
    __syncthreads();                     // bufG reads done; bufP(c1) stores visible

    // ---------- filter c1 (streams g1 to bufG) ----------
    FILTER_PHASE(bufP)
    __syncthreads();

    // ---------- wpost c1 ----------
    if (tid < NN) {
        float s = 0.f;
        #pragma unroll
        for (int w = 0; w < NWAVE; ++w) s += lds_ps[w * NN + tid];
        if constexpr (ATOMIC) atomicAdd(&wpost[tid], s);
        else wpost[(size_t)tid * NCH + c0g + 1] = s;
    }

    // ---------- MFMA c1 (accumulates onto acc) ----------
    MFMA_PHASE(t01)

    // ---------- write partial: wave pair fills disjoint qt of slice (wv&7) ----------
    if constexpr (!ATOMIC) {
        unsigned int* dst = part + ((size_t)bi * 8 + (wv & 7)) * 1024 + lane;
        #pragma unroll
        for (int qi = 0; qi < 4; ++qi) {
            const int qt = qtb + qi;
            dst[qt * 128]      = pack2(acc[qi][0], acc[qi][1]);
            dst[qt * 128 + 64] = pack2(acc[qi][2], acc[qi][3]);
        }
    } else {
        #pragma unroll
        for (int qi = 0; qi < 4; ++qi)
            #pragma unroll
            for (int rg = 0; rg < 4; ++rg) {
                const int prow = pr0 + (lane >> 4) * 4 + rg;
                const int qcol = (qtb + qi) * 16 + (lane & 15);
                atomicAdd(&outat[prow * NN + qcol], acc[qi][rg]);
            }
    }
    #undef FILTER_PHASE
    #undef MFMA_PHASE
}

// fused split-K reduce + hfac + epilogue: 128 blocks x 512 thr.
// Each block's 64 slots share one qt => 16 distinct q: hfac computed in-kernel.
__global__ __launch_bounds__(512)
void finalize_ws(const unsigned int* __restrict__ part, const float* __restrict__ wpost,
                 const int* __restrict__ dtp, const float* __restrict__ W,
                 float* __restrict__ out)
{
    __shared__ float2 red[512];
    __shared__ float  hfs[16];
    const int s    = threadIdx.x & 63;        // slot within block's 64
    const int kq   = threadIdx.x >> 6;        // 0..7
    const int slot = blockIdx.x * 64 + s;     // 0..8191
    const int qt   = (slot >> 7) & 7;         // fixed for whole block
    const int qbase = qt * 16;

    // hfac: 32 threads per q, shfl reduce over wpost[q][0..NCH)
    {
        const int qi = threadIdx.x >> 5;      // 0..15
        const int pr = threadIdx.x & 31;
        float hsum = 0.f;
        const float* wq = wpost + (size_t)(qbase + qi) * NCH;
        #pragma unroll 4
        for (int k = pr; k < NCH; k += 32) hsum += wq[k];
        #pragma unroll
        for (int off = 16; off; off >>= 1) hsum += __shfl_down(hsum, off, 32);
        if (pr == 0) {
            const float dtf   = (float)(*dtp);
            const float alpha = dtf * 1e-3f;
            hfs[qi] = -0.001f * (alpha * (hsum * (1.0f / (float)(BB * TT)) - 0.1f));
        }
    }

    float sx = 0.f, sy = 0.f;
    #pragma unroll 8
    for (int k = kq * (NBLK / 8); k < (kq + 1) * (NBLK / 8); ++k) {
        const unsigned int v = part[(size_t)k * SLOTS + slot];
        const f16x2 h = __builtin_bit_cast(f16x2, v);
        sx += (float)h[0];
        sy += (float)h[1];
    }
    red[threadIdx.x] = make_float2(sx, sy);
    __syncthreads();
    if (threadIdx.x < 64) {
        float tx = red[s].x, ty = red[s].y;
        #pragma unroll
        for (int g = 1; g < 8; ++g) {
            const float2 v = red[g * 64 + s];
            tx += v.x; ty += v.y;
        }
        // un-permute slot -> (p, q)
        const int lane = slot & 63;
        const int rp   = (slot >> 6) & 1;
        const int wv   = slot >> 10;
        const int p    = wv * 16 + ((lane >> 4) << 2) + rp * 2;
        const int qi   = lane & 15;
        const int q    = qbase + qi;
        const float scale = (float)((0.005 - 0.00525) / (double)(BB * TT));
        const float hf = hfs[qi];
        out[p * NN + q]       = fmaf(tx, scale, hf * W[p * NN + q]);
        out[(p + 1) * NN + q] = fmaf(ty, scale, hf * W[(p + 1) * NN + q]);
    }
}

// fallback epilogue when S was atomically accumulated in d_out
__global__ void finalize_at(const float* __restrict__ wpost, const int* __restrict__ dtp,
                            const float* __restrict__ W, float* __restrict__ out)
{
    const int i = (blockIdx.x * 256 + threadIdx.x) * 2;
    const int q = i & 127;
    const float scale = (float)((0.005 - 0.00525) / (double)(BB * TT));
    const float dtf   = (float)(*dtp);
    const float alpha = dtf * 1e-3f;
    const float inv   = 1.0f / (float)(BB * TT);
    const float hf0   = -0.001f * (alpha * (wpost[q]     * inv - 0.1f));
    const float hf1   = -0.001f * (alpha * (wpost[q + 1] * inv - 0.1f));
    float2 sv = *(const float2*)(out + i);
    float2 w  = *(const float2*)(W + i);
    float2 o;
    o.x = fmaf(sv.x, scale, hf0 * w.x);
    o.y = fmaf(sv.y, scale, hf1 * w.y);
    *(float2*)(out + i) = o;
}

extern "C" void kernel_launch(void* const* d_in, const int* in_sizes, int n_in,
                              void* d_out, int out_size, void* d_ws, size_t ws_size,
                              hipStream_t stream)
{
    const float* pre  = (const float*)d_in[0];
    const float* post = (const float*)d_in[1];
    const float* W    = (const float*)d_in[2];
    const int*   dtp  = (const int*)d_in[3];
    float* out = (float*)d_out;

    const size_t part_bytes  = (size_t)NBLK * SLOTS * sizeof(unsigned int); // 8 MiB
    const size_t wpost_bytes = (size_t)NN * NCH * sizeof(float);            // 256 KiB
    const size_t need = part_bytes + wpost_bytes;

    if (ws_size >= need) {
        unsigned int* part = (unsigned int*)d_ws;
        float* wpost       = (float*)((char*)d_ws + part_bytes);
        hipLaunchKernelGGL((stdp_main<false>), dim3(NBLK), dim3(1024), 0, stream,
                           pre, post, dtp, part, wpost, (float*)nullptr);
        hipLaunchKernelGGL(finalize_ws, dim3(SLOTS / 64), dim3(512), 0, stream,
                           part, wpost, dtp, W, out);
    } else {
        // atomic fallback: needs only 512 B of workspace
        float* wpost = (float*)d_ws;
        hipMemsetAsync(d_out, 0, OUTN * sizeof(float), stream);
        hipMemsetAsync(wpost, 0, NN * sizeof(float), stream);
        hipLaunchKernelGGL((stdp_main<true>), dim3(NBLK), dim3(1024), 0, stream,
                           pre, post, dtp, (unsigned int*)nullptr, wpost, out);
        hipLaunchKernelGGL(finalize_at, dim3(OUTN / 512), dim3(256), 0, stream,
                           wpost, dtp, W, out);
    }
}